// Round 1
// baseline (480.596 us; speedup 1.0000x reference)
//
#include <hip/hip_runtime.h>

#define HH 512
#define WW 512
#define MARG 2

// sigmoid(10*t) = 1/(1 + 2^(-10*log2(e)*t)) -> one v_exp_f32 + one v_rcp_f32
__device__ __forceinline__ float sigm(float t) {
    float e = __builtin_amdgcn_exp2f(t * -14.426950408889634f);
    return __builtin_amdgcn_rcpf(1.0f + e);
}

__global__ __launch_bounds__(256) void edge_kernel(const float* __restrict__ x,
                                                   float* __restrict__ out) {
    const int w = blockIdx.x * 64 + (threadIdx.x & 63);
    const int h = blockIdx.y * 4 + (threadIdx.x >> 6);
    const int b = blockIdx.z;

    const bool interior = (h >= MARG) & (h < HH - MARG) & (w >= MARG) & (w < WW - MARG);

    if (!interior) {
        const int base = ((b * 24) * HH + h) * WW + w;
        #pragma unroll
        for (int k = 0; k < 24; ++k) out[base + k * (HH * WW)] = 0.0f;
        return;
    }

    // Load 4(h) x 3(w) window for all 3 channels.
    // r = dh+2 (dh in -2..1), q = dw+1 (dw in -1..1)
    float X[3][4][3];
    #pragma unroll
    for (int j = 0; j < 3; ++j) {
        const float* p = x + ((size_t)(b * 3 + j) * HH + (h - 2)) * WW + (w - 1);
        #pragma unroll
        for (int r = 0; r < 4; ++r)
            #pragma unroll
            for (int q = 0; q < 3; ++q)
                X[j][r][q] = p[r * WW + q];
    }

    // Per-channel cross-channel stash (needed by neighbors via channel rolls):
    // A01[j]   = |diff_01[j,h,w]|      = |X[j][2][0] - X[j][2][1]|
    // An01[j]  = |diff_n01[j,h,w]|     = |X[j][2][2] - X[j][2][1]|
    // rA11[j]  = |diff_11[j,h-1,w]|    = |X[j][0][0] - X[j][1][1]|
    // rAn11[j] = |diff_n11[j,h-1,w]|   = |X[j][2][0] - X[j][1][1]|
    // rA1n1[j] = |diff_1n1[j,h-1,w]|   = |X[j][0][2] - X[j][1][1]|
    float A01[3], An01[3], rA11[3], rAn11[3], rA1n1[3];
    #pragma unroll
    for (int j = 0; j < 3; ++j) {
        const float v = X[j][2][1], u = X[j][1][1];
        A01[j]   = fabsf(X[j][2][0] - v);
        An01[j]  = fabsf(X[j][2][2] - v);
        rA11[j]  = fabsf(X[j][0][0] - u);
        rAn11[j] = fabsf(X[j][2][0] - u);
        rA1n1[j] = fabsf(X[j][0][2] - u);
    }

    #pragma unroll
    for (int c = 0; c < 3; ++c) {
        const int cm = (c + 2) % 3, cp = (c + 1) % 3;
        const float v = X[c][2][1], u = X[c][1][1];

        const float d10   = u            - v;   // x[h-1,w]   - x[h,w]
        const float dn10  = X[c][3][1]   - v;   // x[h+1,w]   - x
        const float d01   = X[c][2][0]   - v;   // x[h,w-1]   - x
        const float dn01  = X[c][2][2]   - v;   // x[h,w+1]   - x
        const float d11   = X[c][1][0]   - v;   // x[h-1,w-1] - x
        const float dnn11 = X[c][3][2]   - v;   // x[h+1,w+1] - x
        const float dn11  = X[c][3][0]   - v;   // x[h+1,w-1] - x
        const float d1n1  = X[c][1][2]   - v;   // x[h-1,w+1] - x
        const float r_d10 = X[c][0][1]   - u;   // diff_10 at (h-1,w)
        const float r_d01 = X[c][1][0]   - u;   // diff_01 at (h-1,w)
        // |diff_n10 at (h-1,w)| = |v - u| = |d10|

        const int obase = ((b * 24 + c * 8) * HH + h) * WW + w;
        const int plane = HH * WW;

        // ---- branch 10 ----
        const float a10  = fabsf(d10);
        const float ad10 = a10 * sigm(a10);                       // ad_10 * gt(ad_10 - DTR)
        const float e10s = sigm(ad10 - fabsf(d01)) + sigm(ad10 - fabsf(dn01)) + sigm(ad10 - fabsf(dn10))
                         + 2.0f * sigm(ad10 - A01[cm])            // rl(diff_01,(1,0)) term appears twice
                         + sigm(ad10 - An01[cm]);
        const float g10 = sigm(e10s - 4.0f);
        const float s10 = sigm(d10);
        out[obase + 0 * plane] = g10 * s10;
        out[obase + 1 * plane] = g10 * (1.0f - s10);

        // ---- branch 01 ----  (NOTE: scaled by sigm(updated ad_10) per reference)
        const float ad01 = fabsf(d01) * sigm(ad10);
        const float e01s = sigm(ad01 - a10) + sigm(ad01 - fabsf(dn10)) + sigm(ad01 - fabsf(dn01))
                         + sigm(ad01 - fabsf(r_d10)) + sigm(ad01 - a10) + sigm(ad01 - fabsf(r_d01));
        const float g01 = sigm(e01s - 4.0f);
        const float e01 = g01 * sigm(d01);
        out[obase + 2 * plane] = e01;
        out[obase + 3 * plane] = e01;                             // reference: e01n == e01

        // ---- branch 11 ----
        const float a11  = fabsf(d11);
        const float ad11 = a11 * sigm(a11);
        const float e11s = sigm(ad11 - fabsf(dn11)) + sigm(ad11 - fabsf(d1n1)) + sigm(ad11 - fabsf(dnn11))
                         + sigm(ad11 - rAn11[cm]) + sigm(ad11 - rA1n1[cm]) + sigm(ad11 - rA11[cm]);
        const float g11 = sigm(e11s - 4.0f);
        const float s11 = sigm(d11);
        out[obase + 4 * plane] = g11 * s11;
        out[obase + 5 * plane] = g11 * (1.0f - s11);

        // ---- branch n11 ----  (hard >0 mask is numerically identity: |d|*(|d|>0) == |d|)
        const float adn11 = fabsf(dn11);
        const float en11s = sigm(adn11 - a11) + sigm(adn11 - fabsf(d1n1)) + sigm(adn11 - fabsf(dnn11))
                          + sigm(adn11 - rA11[cp])
                          + 2.0f * sigm(adn11 - rAn11[cp]);       // rl(diff_n11,(-1,1)) appears twice
        const float gn11 = sigm(en11s - 4.0f);
        const float sn11 = sigm(dn11);
        out[obase + 6 * plane] = gn11 * sn11;
        out[obase + 7 * plane] = gn11 * (1.0f - sn11);
    }
}

extern "C" void kernel_launch(void* const* d_in, const int* in_sizes, int n_in,
                              void* d_out, int out_size, void* d_ws, size_t ws_size,
                              hipStream_t stream) {
    const float* x = (const float*)d_in[0];
    float* out = (float*)d_out;
    dim3 grid(WW / 64, HH / 4, 16);   // (8, 128, 16)
    dim3 block(256);                  // wave = one row of 64 consecutive w -> coalesced
    edge_kernel<<<grid, block, 0, stream>>>(x, out);
}

// Round 2
// 454.011 us; speedup vs baseline: 1.0586x; 1.0586x over previous
//
#include <hip/hip_runtime.h>

#define HH 512
#define WW 512

// sigmoid(10*t) = 1/(1 + 2^(-10*log2(e)*t)) -> one v_exp_f32 + one v_rcp_f32
__device__ __forceinline__ float sigm(float t) {
    float e = __builtin_amdgcn_exp2f(t * -14.426950408889634f);
    return __builtin_amdgcn_rcpf(1.0f + e);
}

__global__ __launch_bounds__(256) void edge_kernel(const float* __restrict__ x,
                                                   float* __restrict__ out) {
    const int tx = threadIdx.x & 63;          // 64 lanes along w, 4 px each
    const int ty = threadIdx.x >> 6;          // 4 rows per block
    const int w0 = blockIdx.x * 256 + tx * 4; // aligned float4 start
    const int h  = blockIdx.y * 4 + ty;
    const int b  = blockIdx.z;

    float4* outp = (float4*)(out + (((size_t)(b * 24) * HH + h) * WW + w0));
    const int PL = HH * WW / 4;               // plane stride in float4 units

    // h-exterior rows are entirely zero: wave-uniform branch
    if (h < 2 || h >= HH - 2) {
        const float4 z = make_float4(0.f, 0.f, 0.f, 0.f);
        #pragma unroll
        for (int k = 0; k < 24; ++k) outp[k * PL] = z;
        return;
    }

    // Window W6[ch][row][col]: rows h-2..h+1, cols w0-1..w0+4.
    // Aligned float4 for the middle 4, clamped scalars for the edges
    // (clamped values only feed w-masked pixels -> numerically irrelevant).
    float W6[3][4][6];
    const int wl = (w0 == 0) ? 0 : (w0 - 1);
    const int wr = (w0 + 4 >= WW) ? (WW - 1) : (w0 + 4);
    #pragma unroll
    for (int j = 0; j < 3; ++j) {
        const float* rp = x + (((size_t)(b * 3 + j) * HH + (h - 2)) * WW);
        #pragma unroll
        for (int r = 0; r < 4; ++r) {
            const float* row = rp + r * WW;
            const float4 m = *(const float4*)(row + w0);
            W6[j][r][0] = row[wl];
            W6[j][r][1] = m.x; W6[j][r][2] = m.y;
            W6[j][r][3] = m.z; W6[j][r][4] = m.w;
            W6[j][r][5] = row[wr];
        }
    }

    #pragma unroll
    for (int c = 0; c < 3; ++c) {
        const int cm = (c + 2) % 3, cp = (c + 1) % 3;
        float acc[8][4];
        #pragma unroll
        for (int q = 0; q < 4; ++q) {
            const float v = W6[c][2][q + 1], u = W6[c][1][q + 1];
            const float d10   = u              - v;   // x[h-1,w]   - x
            const float dn10  = W6[c][3][q+1]  - v;   // x[h+1,w]   - x
            const float d01   = W6[c][2][q]    - v;   // x[h,w-1]   - x
            const float dn01  = W6[c][2][q+2]  - v;   // x[h,w+1]   - x
            const float d11   = W6[c][1][q]    - v;   // x[h-1,w-1] - x
            const float dnn11 = W6[c][3][q+2]  - v;   // x[h+1,w+1] - x
            const float dn11  = W6[c][3][q]    - v;   // x[h+1,w-1] - x
            const float d1n1  = W6[c][1][q+2]  - v;   // x[h-1,w+1] - x
            const float r_d10 = W6[c][0][q+1]  - u;   // diff_10 @ (h-1,w)
            const float r_d01 = W6[c][1][q]    - u;   // diff_01 @ (h-1,w)

            // cross-channel neighbor diffs, recomputed on the fly (reg save)
            const float A01m   = fabsf(W6[cm][2][q]   - W6[cm][2][q+1]);
            const float An01m  = fabsf(W6[cm][2][q+2] - W6[cm][2][q+1]);
            const float rA11m  = fabsf(W6[cm][0][q]   - W6[cm][1][q+1]);
            const float rAn11m = fabsf(W6[cm][2][q]   - W6[cm][1][q+1]);
            const float rA1n1m = fabsf(W6[cm][0][q+2] - W6[cm][1][q+1]);
            const float rA11p  = fabsf(W6[cp][0][q]   - W6[cp][1][q+1]);
            const float rAn11p = fabsf(W6[cp][2][q]   - W6[cp][1][q+1]);

            // w-exterior pixels are zeroed via the g gates
            const float msk = ((w0 + q) >= 2 && (w0 + q) < WW - 2) ? 1.0f : 0.0f;

            // ---- branch 10 ----
            const float a10  = fabsf(d10);
            const float ad10 = a10 * sigm(a10);
            const float e10s = sigm(ad10 - fabsf(d01)) + sigm(ad10 - fabsf(dn01))
                             + sigm(ad10 - fabsf(dn10))
                             + 2.0f * sigm(ad10 - A01m)       // repeated term in ref
                             + sigm(ad10 - An01m);
            const float g10 = msk * sigm(e10s - 4.0f);
            const float s10 = sigm(d10);
            acc[0][q] = g10 * s10;
            acc[1][q] = g10 * (1.0f - s10);

            // ---- branch 01 ---- (scaled by sigm(updated ad_10), per ref)
            const float ad01 = fabsf(d01) * sigm(ad10);
            const float e01s = 2.0f * sigm(ad01 - a10)        // term appears twice
                             + sigm(ad01 - fabsf(dn10)) + sigm(ad01 - fabsf(dn01))
                             + sigm(ad01 - fabsf(r_d10)) + sigm(ad01 - fabsf(r_d01));
            const float g01 = msk * sigm(e01s - 4.0f);
            const float e01 = g01 * sigm(d01);
            acc[2][q] = e01;
            acc[3][q] = e01;                                   // ref: e01n == e01

            // ---- branch 11 ----
            const float a11  = fabsf(d11);
            const float ad11 = a11 * sigm(a11);
            const float e11s = sigm(ad11 - fabsf(dn11)) + sigm(ad11 - fabsf(d1n1))
                             + sigm(ad11 - fabsf(dnn11))
                             + sigm(ad11 - rAn11m) + sigm(ad11 - rA1n1m)
                             + sigm(ad11 - rA11m);
            const float g11 = msk * sigm(e11s - 4.0f);
            const float s11 = sigm(d11);
            acc[4][q] = g11 * s11;
            acc[5][q] = g11 * (1.0f - s11);

            // ---- branch n11 ---- (hard >0 mask is identity)
            const float adn11 = fabsf(dn11);
            const float en11s = sigm(adn11 - a11) + sigm(adn11 - fabsf(d1n1))
                              + sigm(adn11 - fabsf(dnn11))
                              + sigm(adn11 - rA11p)
                              + 2.0f * sigm(adn11 - rAn11p);   // repeated term in ref
            const float gn11 = msk * sigm(en11s - 4.0f);
            const float sn11 = sigm(dn11);
            acc[6][q] = gn11 * sn11;
            acc[7][q] = gn11 * (1.0f - sn11);
        }
        #pragma unroll
        for (int k = 0; k < 8; ++k)
            outp[(c * 8 + k) * PL] = make_float4(acc[k][0], acc[k][1], acc[k][2], acc[k][3]);
    }
}

extern "C" void kernel_launch(void* const* d_in, const int* in_sizes, int n_in,
                              void* d_out, int out_size, void* d_ws, size_t ws_size,
                              hipStream_t stream) {
    const float* x = (const float*)d_in[0];
    float* out = (float*)d_out;
    dim3 grid(WW / 256, HH / 4, 16);   // (2, 128, 16)
    dim3 block(256);                   // wave = 64 lanes x 4 px = 256 contiguous w
    edge_kernel<<<grid, block, 0, stream>>>(x, out);
}